// Round 1
// baseline (820.286 us; speedup 1.0000x reference)
//
#include <hip/hip_runtime.h>
#include <cstdint>
#include <cstddef>

// Problem constants (fixed by reference)
#define BATCH 32
#define SEQ   2048
#define DIM   1024      // ENC_D = DEC_D = ATTN_D = OUT_D = 1024
#define MROWS (BATCH*SEQ)   // 65536

typedef __attribute__((ext_vector_type(4))) float  floatx4;
typedef __attribute__((ext_vector_type(8))) short  short8;

// fp32 -> bf16 round-to-nearest-even (software; RTNE matches __float2bfloat16)
__device__ __forceinline__ unsigned short f2bf(float f) {
  unsigned int u = __float_as_uint(f);
  u += 0x7fffu + ((u >> 16) & 1u);
  return (unsigned short)(u >> 16);
}

// async global->LDS, 16B per lane; LDS dest = wave-uniform base + lane*16
__device__ __forceinline__ void async16(const void* g, void* l) {
  __builtin_amdgcn_global_load_lds(
      (const __attribute__((address_space(1))) unsigned int*)g,
      (__attribute__((address_space(3))) unsigned int*)l, 16, 0, 0);
}

__device__ __forceinline__ float fast_tanh(float x) {
  // tanh(x) = 1 - 2/(1+e^{2x}); v_exp + v_rcp, rel err ~1e-6 (budget is ~2e-2)
  float e = __expf(2.0f * x);
  return 1.0f - 2.0f * __builtin_amdgcn_rcpf(1.0f + e);
}

// ---------------------------------------------------------------------------
// Kernel 1: Wt[n][k] = bf16(W_enc[k][n])  (1024x1024)
// ---------------------------------------------------------------------------
__global__ void k_transpose(const float* __restrict__ W, unsigned short* __restrict__ Wt) {
  __shared__ float tile[32][33];
  int n0 = blockIdx.x * 32, k0 = blockIdx.y * 32;
  int tx = threadIdx.x, ty = threadIdx.y;   // (32, 8)
#pragma unroll
  for (int i = 0; i < 4; ++i) {
    int y = ty + i * 8;
    tile[y][tx] = W[(size_t)(k0 + y) * DIM + n0 + tx];
  }
  __syncthreads();
#pragma unroll
  for (int i = 0; i < 4; ++i) {
    int y = ty + i * 8;
    Wt[(size_t)(n0 + y) * DIM + k0 + tx] = f2bf(tile[tx][y]);
  }
}

// ---------------------------------------------------------------------------
// Kernel 2: dech[b][a] = dec_states[b] @ W_dec[:,a] + b_dec[a] + b_enc[a]
// ---------------------------------------------------------------------------
__global__ void k_dech(const float* __restrict__ dec, const float* __restrict__ W_dec,
                       const float* __restrict__ b_dec, const float* __restrict__ b_enc,
                       float* __restrict__ dech) {
  int b = blockIdx.y;
  int a = blockIdx.x * 256 + threadIdx.x;
  float acc = b_dec[a] + b_enc[a];
  const float* dr = dec + (size_t)b * DIM;
#pragma unroll 4
  for (int e = 0; e < DIM; ++e)
    acc = fmaf(dr[e], W_dec[(size_t)e * DIM + a], acc);
  dech[(size_t)b * DIM + a] = acc;
}

// ---------------------------------------------------------------------------
// Kernel 3: fused GEMM + tanh-dot epilogue.
//   score[m] += sum_n tanh( (enc@W_enc)[m][n] + dech[b(m)][n] ) * w_attn[n]
// 128x128 tile, BK=32, 16x16x32 bf16 MFMA, 4 waves (2x2 of 64x64).
// ---------------------------------------------------------------------------
__global__ void __launch_bounds__(256, 2) k_gemm_attn(
    const float* __restrict__ A,            // enc_states [65536,1024] fp32
    const unsigned short* __restrict__ Wt,  // [1024 n][1024 k] bf16
    const float* __restrict__ dech,         // [32,1024]
    const float* __restrict__ w_attn,       // [1024]
    const int* __restrict__ enc_len,        // [32]
    float* __restrict__ score)              // [65536], pre-zeroed
{
  // XCD swizzle: 8 column-blocks of a row panel land temporally adjacent on
  // the same XCD (linear dispatch round-robins blockIdx % 8 across XCDs).
  int linear = blockIdx.x;          // 0..4095
  int xcd = linear & 7;
  int j   = linear >> 3;            // 0..511
  int rb  = xcd * 64 + (j >> 3);    // row block 0..511
  int nb  = j & 7;                  // col block 0..7

  int bb  = rb >> 4;                // batch index (2048/128 = 16 row blocks per b)
  int len = enc_len[bb];
  if (((rb & 15) * 128) >= len) return;   // whole tile masked -> softmax ignores

  __shared__ __align__(16) unsigned short sA[128 * 40];  // 40 = 32 + 8 pad (80B rows)
  __shared__ __align__(16) unsigned short sB[128 * 32];  // linear [n][k], XOR-swizzled

  int tid  = threadIdx.x;
  int w    = tid >> 6, lane = tid & 63;
  int wm   = (w >> 1) * 64, wn = (w & 1) * 64;
  int li   = lane & 15, g = lane >> 4;

  const float*          Abase = A  + (size_t)rb * 128 * DIM;
  const unsigned short* Bbase = Wt + (size_t)nb * 128 * DIM;

  floatx4 acc[4][4] = {};

  for (int kb = 0; kb < 32; ++kb) {
    __syncthreads();
    // --- stage B: async 16B/lane from pre-transposed bf16 Wt ---
    // physical chunk p = (w*2+i)*64 + lane; content n = p>>2,
    // logical k-half = (p&3) ^ ((n>>1)&3)  (XOR swizzle -> 2-way-max conflicts)
#pragma unroll
    for (int i = 0; i < 2; ++i) {
      int c  = (w * 2 + i) * 64 + lane;
      int n  = c >> 2;
      int kh = (c & 3) ^ ((n >> 1) & 3);
      const unsigned short* gp = Bbase + (size_t)n * DIM + kb * 32 + kh * 8;
      async16(gp, (char*)sB + (w * 2 + i) * 1024);
    }
    // --- stage A: fp32 float4 load -> bf16 RTNE -> ds_write_b64 ---
#pragma unroll
    for (int i = 0; i < 4; ++i) {
      int f4  = tid + i * 256;
      int row = f4 >> 3, kq = f4 & 7;
      float4 v = *(const float4*)(Abase + (size_t)row * DIM + kb * 32 + kq * 4);
      ushort4 h;
      h.x = f2bf(v.x); h.y = f2bf(v.y); h.z = f2bf(v.z); h.w = f2bf(v.w);
      *(ushort4*)&sA[row * 40 + kq * 4] = h;
    }
    __syncthreads();   // compiler emits waitcnt vmcnt(0) lgkmcnt(0) before barrier

    // --- fragments + 16 MFMA ---
    short8 af[4], bf[4];
#pragma unroll
    for (int t = 0; t < 4; ++t) {
      int row = wm + t * 16 + li;
      af[t] = *(const short8*)&sA[row * 40 + g * 8];
      int nl = wn + t * 16 + li;
      int phys = (nl << 2) | (g ^ ((nl >> 1) & 3));
      bf[t] = *(const short8*)((const char*)sB + phys * 16);
    }
#pragma unroll
    for (int tm = 0; tm < 4; ++tm)
#pragma unroll
      for (int tn = 0; tn < 4; ++tn)
        acc[tm][tn] = __builtin_amdgcn_mfma_f32_16x16x32_bf16(af[tm], bf[tn], acc[tm][tn], 0, 0, 0);
  }

  // --- epilogue: t = tanh(c + dech)·w_attn, reduce 16 cols/lane-group, atomic per row
  // C/D layout: col = lane&15, row = (lane>>4)*4 + reg   [m89]
  float dh[4], wa[4];
#pragma unroll
  for (int tn = 0; tn < 4; ++tn) {
    int n = nb * 128 + wn + tn * 16 + li;
    dh[tn] = dech[(size_t)bb * DIM + n];
    wa[tn] = w_attn[n];
  }
#pragma unroll
  for (int tm = 0; tm < 4; ++tm) {
    int mrow = rb * 128 + wm + tm * 16 + g * 4;
#pragma unroll
    for (int r = 0; r < 4; ++r) {
      float v = 0.0f;
#pragma unroll
      for (int tn = 0; tn < 4; ++tn)
        v = fmaf(wa[tn], fast_tanh(acc[tm][tn][r] + dh[tn]), v);
      v += __shfl_xor(v, 1);
      v += __shfl_xor(v, 2);
      v += __shfl_xor(v, 4);
      v += __shfl_xor(v, 8);
      if (li == 0) atomicAdd(&score[mrow + r], v);
    }
  }
}

// ---------------------------------------------------------------------------
// Kernel 4: masked softmax per batch row. SCALING == 1.0 (folded out).
// ---------------------------------------------------------------------------
__global__ void k_softmax(const float* __restrict__ score, const int* __restrict__ enc_len,
                          float* __restrict__ attn) {
  int b = blockIdx.x, tid = threadIdx.x;
  int len = enc_len[b];
  __shared__ float red[256];
  float v[8];
  float m = -1e30f;
#pragma unroll
  for (int i = 0; i < 8; ++i) {
    int s = tid + i * 256;
    v[i] = score[(size_t)b * SEQ + s];
    if (s < len) m = fmaxf(m, v[i]);
  }
  red[tid] = m; __syncthreads();
  for (int st = 128; st > 0; st >>= 1) {
    if (tid < st) red[tid] = fmaxf(red[tid], red[tid + st]);
    __syncthreads();
  }
  float mx = red[0]; __syncthreads();
  float sum = 0.0f;
#pragma unroll
  for (int i = 0; i < 8; ++i) {
    int s = tid + i * 256;
    float e = (s < len) ? __expf(v[i] - mx) : 0.0f;
    v[i] = e; sum += e;
  }
  red[tid] = sum; __syncthreads();
  for (int st = 128; st > 0; st >>= 1) {
    if (tid < st) red[tid] += red[tid + st];
    __syncthreads();
  }
  float inv = 1.0f / red[0];
#pragma unroll
  for (int i = 0; i < 8; ++i)
    attn[(size_t)b * SEQ + tid + i * 256] = v[i] * inv;
}

// ---------------------------------------------------------------------------
// Kernel 5: ctx[b][e] += sum_s attn[b][s] * enc[b][s][e]   (memory-bound)
// grid (16 s-chunks of 128, 32 b), 256 thr, 4 floats/thread
// ---------------------------------------------------------------------------
__global__ void k_context(const float* __restrict__ enc, const float* __restrict__ attn,
                          const int* __restrict__ enc_len, float* __restrict__ ctx) {
  int b = blockIdx.y, sc = blockIdx.x;
  int len = enc_len[b];
  int s0 = sc * 128;
  if (s0 >= len) return;          // attn exactly 0 there
  int cnt = min(128, len - s0);
  int tid = threadIdx.x;
  const float* base = enc + ((size_t)b * SEQ + s0) * DIM + tid * 4;
  const float* ap   = attn + (size_t)b * SEQ + s0;
  float a0 = 0.f, a1 = 0.f, a2 = 0.f, a3 = 0.f;
  for (int i = 0; i < cnt; ++i) {
    float a = ap[i];
    float4 x = *(const float4*)(base + (size_t)i * DIM);
    a0 = fmaf(a, x.x, a0); a1 = fmaf(a, x.y, a1);
    a2 = fmaf(a, x.z, a2); a3 = fmaf(a, x.w, a3);
  }
  float* c = ctx + (size_t)b * DIM + tid * 4;
  atomicAdd(c + 0, a0); atomicAdd(c + 1, a1);
  atomicAdd(c + 2, a2); atomicAdd(c + 3, a3);
}

// ---------------------------------------------------------------------------
// Kernel 6: out[b][o] = ctx[b] @ W_out[:,o] + b_out[o]
// ---------------------------------------------------------------------------
__global__ void k_out(const float* __restrict__ ctx, const float* __restrict__ W_out,
                      const float* __restrict__ b_out, float* __restrict__ out) {
  int b = blockIdx.y;
  int o = blockIdx.x * 256 + threadIdx.x;
  float acc = b_out[o];
  const float* cr = ctx + (size_t)b * DIM;
#pragma unroll 4
  for (int e = 0; e < DIM; ++e)
    acc = fmaf(cr[e], W_out[(size_t)e * DIM + o], acc);
  out[(size_t)b * DIM + o] = acc;
}

// ---------------------------------------------------------------------------
extern "C" void kernel_launch(void* const* d_in, const int* in_sizes, int n_in,
                              void* d_out, int out_size, void* d_ws, size_t ws_size,
                              hipStream_t stream) {
  (void)in_sizes; (void)n_in; (void)out_size; (void)ws_size;
  const float* enc_states = (const float*)d_in[0];   // [32,2048,1024]
  const float* dec_states = (const float*)d_in[1];   // [32,1024]
  const float* W_enc      = (const float*)d_in[2];   // [1024,1024]
  const float* b_enc      = (const float*)d_in[3];   // [1024]
  const float* W_dec      = (const float*)d_in[4];   // [1024,1024]
  const float* b_dec      = (const float*)d_in[5];   // [1024]
  const float* w_attn     = (const float*)d_in[6];   // [1024]
  const float* W_out      = (const float*)d_in[7];   // [1024,1024]
  const float* b_out      = (const float*)d_in[8];   // [1024]
  const int*   enc_len    = (const int*)  d_in[9];   // [32]

  float* out_ctx  = (float*)d_out;                   // [32,1024]
  float* out_attn = (float*)d_out + BATCH * DIM;     // [32,2048]

  // workspace layout (2.625 MB total)
  char* ws = (char*)d_ws;
  unsigned short* Wt  = (unsigned short*)ws;                       // 2 MB
  float* score = (float*)(ws + (2u << 20));                        // 256 KB
  float* ctx   = (float*)(ws + (2u << 20) + 262144);               // 128 KB
  float* dech  = (float*)(ws + (2u << 20) + 262144 + 131072);      // 128 KB (fully written)

  // zero score + ctx (atomically accumulated)
  hipMemsetAsync(ws + (2u << 20), 0, 262144 + 131072, stream);

  k_transpose<<<dim3(32, 32), dim3(32, 8), 0, stream>>>(W_enc, Wt);
  k_dech<<<dim3(4, BATCH), 256, 0, stream>>>(dec_states, W_dec, b_dec, b_enc, dech);
  k_gemm_attn<<<4096, 256, 0, stream>>>(enc_states, Wt, dech, w_attn, enc_len, score);
  k_softmax<<<BATCH, 256, 0, stream>>>(score, enc_len, out_attn);
  k_context<<<dim3(16, BATCH), 256, 0, stream>>>(enc_states, out_attn, enc_len, ctx);
  k_out<<<dim3(4, BATCH), 256, 0, stream>>>(ctx, W_out, b_out, out_ctx);
}

// Round 2
// 613.465 us; speedup vs baseline: 1.3371x; 1.3371x over previous
//
#include <hip/hip_runtime.h>
#include <cstdint>
#include <cstddef>

// Problem constants (fixed by reference)
#define BATCH 32
#define SEQ   2048
#define DIM   1024      // ENC_D = DEC_D = ATTN_D = OUT_D = 1024
#define MROWS (BATCH*SEQ)   // 65536

typedef __attribute__((ext_vector_type(4))) float  floatx4;
typedef __attribute__((ext_vector_type(8))) short  short8;

// fp32 -> bf16 round-to-nearest-even
__device__ __forceinline__ unsigned short f2bf(float f) {
  unsigned int u = __float_as_uint(f);
  u += 0x7fffu + ((u >> 16) & 1u);
  return (unsigned short)(u >> 16);
}

// async global->LDS, 16B per lane; LDS dest = wave-uniform base + lane*16
__device__ __forceinline__ void async16(const void* g, void* l) {
  __builtin_amdgcn_global_load_lds(
      (const __attribute__((address_space(1))) unsigned int*)g,
      (__attribute__((address_space(3))) unsigned int*)l, 16, 0, 0);
}

__device__ __forceinline__ float fast_tanh(float x) {
  float e = __expf(2.0f * x);
  return 1.0f - 2.0f * __builtin_amdgcn_rcpf(1.0f + e);
}

// ---------------------------------------------------------------------------
// Kernel 0: Abf[b][s][k] = bf16(enc_states[b][s][k]); rows >= len skipped
// (GEMM tiles covering them read poison, which is a tiny bf16 value; those
//  score rows are masked in softmax, so garbage never propagates.)
// ---------------------------------------------------------------------------
__global__ void k_convert(const float* __restrict__ enc, const int* __restrict__ enc_len,
                          unsigned short* __restrict__ Abf) {
  int b = blockIdx.y;
  int r0 = blockIdx.x * 8;                 // 8 rows per block
  if (r0 >= enc_len[b]) return;
  size_t base = ((size_t)b * SEQ + r0) * DIM;
  const float4* src = (const float4*)(enc + base);
  ushort4* dst = (ushort4*)(Abf + base);
  int tid = threadIdx.x;
#pragma unroll
  for (int i = 0; i < 8; ++i) {
    float4 v = src[tid + i * 256];
    ushort4 h;
    h.x = f2bf(v.x); h.y = f2bf(v.y); h.z = f2bf(v.z); h.w = f2bf(v.w);
    dst[tid + i * 256] = h;
  }
}

// ---------------------------------------------------------------------------
// Kernel 1: Wt[n][k] = bf16(W_enc[k][n])  (1024x1024)
// ---------------------------------------------------------------------------
__global__ void k_transpose(const float* __restrict__ W, unsigned short* __restrict__ Wt) {
  __shared__ float tile[32][33];
  int n0 = blockIdx.x * 32, k0 = blockIdx.y * 32;
  int tx = threadIdx.x, ty = threadIdx.y;   // (32, 8)
#pragma unroll
  for (int i = 0; i < 4; ++i) {
    int y = ty + i * 8;
    tile[y][tx] = W[(size_t)(k0 + y) * DIM + n0 + tx];
  }
  __syncthreads();
#pragma unroll
  for (int i = 0; i < 4; ++i) {
    int y = ty + i * 8;
    Wt[(size_t)(n0 + y) * DIM + k0 + tx] = f2bf(tile[tx][y]);
  }
}

// ---------------------------------------------------------------------------
// Kernel 2: dech[b][a] += dec_states[b, z-chunk] @ W_dec[z-chunk, a]
// split-K x8 (grid.z) for parallelism; chunk 0 adds biases; dech pre-zeroed
// ---------------------------------------------------------------------------
__global__ void k_dech(const float* __restrict__ dec, const float* __restrict__ W_dec,
                       const float* __restrict__ b_dec, const float* __restrict__ b_enc,
                       float* __restrict__ dech) {
  int b = blockIdx.y, z = blockIdx.z;
  int a = blockIdx.x * 256 + threadIdx.x;
  float acc = (z == 0) ? (b_dec[a] + b_enc[a]) : 0.0f;
  const float* dr = dec + (size_t)b * DIM + z * 128;
  const float* wc = W_dec + (size_t)z * 128 * DIM + a;
#pragma unroll 8
  for (int e = 0; e < 128; ++e)
    acc = fmaf(dr[e], wc[(size_t)e * DIM], acc);
  atomicAdd(&dech[(size_t)b * DIM + a], acc);
}

// ---------------------------------------------------------------------------
// Kernel 3 (fast path): m97-structure GEMM + tanh-dot epilogue, bf16 A.
//   score[m] += sum_n tanh( (enc@W_enc)[m][n] + dech[b(m)][n] ) * w_attn[n]
// 128x128 tile, BK=32, 16x16x32 bf16 MFMA, 4 waves (2x2 of 64x64).
// Both operands staged via global_load_lds width=16 into linear 64B-row LDS;
// ds_read_b128 fragment reads from 64B rows are bank-balanced (8/bank).
// ---------------------------------------------------------------------------
__global__ void __launch_bounds__(256, 2) k_gemm_bf16(
    const unsigned short* __restrict__ Abf, // [65536,1024] bf16
    const unsigned short* __restrict__ Wt,  // [1024 n][1024 k] bf16
    const float* __restrict__ dech,         // [32,1024]
    const float* __restrict__ w_attn,       // [1024]
    const int* __restrict__ enc_len,        // [32]
    float* __restrict__ score)              // [65536], pre-zeroed
{
  int linear = blockIdx.x;          // 0..4095
  int xcd = linear & 7;
  int j   = linear >> 3;
  int rb  = xcd * 64 + (j >> 3);    // row block 0..511 (8 col-blocks adjacent per XCD)
  int nb  = j & 7;                  // col block 0..7

  int bb  = rb >> 4;
  int len = enc_len[bb];
  if (((rb & 15) * 128) >= len) return;   // fully masked tile

  __shared__ __align__(16) unsigned short sA[128 * 32];  // 8 KB, 64B per row
  __shared__ __align__(16) unsigned short sB[128 * 32];  // 8 KB, 64B per n-row

  int tid  = threadIdx.x;
  int w    = tid >> 6, lane = tid & 63;
  int wm   = (w >> 1) * 64, wn = (w & 1) * 64;
  int li   = lane & 15, g = lane >> 4;

  const unsigned short* Ab = Abf + (size_t)rb * 128 * DIM;
  const unsigned short* Bb = Wt  + (size_t)nb * 128 * DIM;

  floatx4 acc[4][4] = {};

  for (int kb = 0; kb < 32; ++kb) {
    __syncthreads();
    // stage A and B: chunk p holds row p>>2, k-quarter p&3 (8 bf16 = 16 B)
#pragma unroll
    for (int r = 0; r < 2; ++r) {
      int seg = r * 4 + w;                 // 0..7 (wave-uniform)
      int p   = seg * 64 + lane;           // 0..511
      int row = p >> 2, q = p & 3;
      size_t goff = (size_t)row * DIM + kb * 32 + q * 8;
      async16(Ab + goff, (char*)sA + seg * 1024);
      async16(Bb + goff, (char*)sB + seg * 1024);
    }
    __syncthreads();

    short8 af[4], bfr[4];
#pragma unroll
    for (int t = 0; t < 4; ++t) {
      int row = wm + t * 16 + li;
      af[t]  = *(const short8*)&sA[(row * 4 + g) * 8];
      int n  = wn + t * 16 + li;
      bfr[t] = *(const short8*)&sB[(n * 4 + g) * 8];
    }
#pragma unroll
    for (int tm = 0; tm < 4; ++tm)
#pragma unroll
      for (int tn = 0; tn < 4; ++tn)
        acc[tm][tn] = __builtin_amdgcn_mfma_f32_16x16x32_bf16(af[tm], bfr[tn], acc[tm][tn], 0, 0, 0);
  }

  // epilogue: C/D layout col=lane&15, row=(lane>>4)*4+reg  [m89]
  float dh[4], wa[4];
#pragma unroll
  for (int tn = 0; tn < 4; ++tn) {
    int n = nb * 128 + wn + tn * 16 + li;
    dh[tn] = dech[(size_t)bb * DIM + n];
    wa[tn] = w_attn[n];
  }
#pragma unroll
  for (int tm = 0; tm < 4; ++tm) {
    int mrow = rb * 128 + wm + tm * 16 + g * 4;
#pragma unroll
    for (int r = 0; r < 4; ++r) {
      float v = 0.0f;
#pragma unroll
      for (int tn = 0; tn < 4; ++tn)
        v = fmaf(wa[tn], fast_tanh(acc[tm][tn][r] + dh[tn]), v);
      v += __shfl_xor(v, 1);
      v += __shfl_xor(v, 2);
      v += __shfl_xor(v, 4);
      v += __shfl_xor(v, 8);
      if (li == 0) atomicAdd(&score[mrow + r], v);
    }
  }
}

// ---------------------------------------------------------------------------
// Kernel 3 (fallback, ws too small): previous fp32-staging GEMM (passing)
// ---------------------------------------------------------------------------
__global__ void __launch_bounds__(256, 2) k_gemm_f32(
    const float* __restrict__ A, const unsigned short* __restrict__ Wt,
    const float* __restrict__ dech, const float* __restrict__ w_attn,
    const int* __restrict__ enc_len, float* __restrict__ score)
{
  int linear = blockIdx.x;
  int xcd = linear & 7;
  int j   = linear >> 3;
  int rb  = xcd * 64 + (j >> 3);
  int nb  = j & 7;
  int bb  = rb >> 4;
  int len = enc_len[bb];
  if (((rb & 15) * 128) >= len) return;

  __shared__ __align__(16) unsigned short sA[128 * 40];
  __shared__ __align__(16) unsigned short sB[128 * 32];

  int tid  = threadIdx.x;
  int w    = tid >> 6, lane = tid & 63;
  int wm   = (w >> 1) * 64, wn = (w & 1) * 64;
  int li   = lane & 15, g = lane >> 4;

  const float*          Abase = A  + (size_t)rb * 128 * DIM;
  const unsigned short* Bbase = Wt + (size_t)nb * 128 * DIM;

  floatx4 acc[4][4] = {};

  for (int kb = 0; kb < 32; ++kb) {
    __syncthreads();
#pragma unroll
    for (int i = 0; i < 2; ++i) {
      int c  = (w * 2 + i) * 64 + lane;
      int n  = c >> 2;
      int kh = (c & 3) ^ ((n >> 1) & 3);
      async16(Bbase + (size_t)n * DIM + kb * 32 + kh * 8, (char*)sB + (w * 2 + i) * 1024);
    }
#pragma unroll
    for (int i = 0; i < 4; ++i) {
      int f4  = tid + i * 256;
      int row = f4 >> 3, kq = f4 & 7;
      float4 v = *(const float4*)(Abase + (size_t)row * DIM + kb * 32 + kq * 4);
      ushort4 h;
      h.x = f2bf(v.x); h.y = f2bf(v.y); h.z = f2bf(v.z); h.w = f2bf(v.w);
      *(ushort4*)&sA[row * 40 + kq * 4] = h;
    }
    __syncthreads();

    short8 af[4], bfr[4];
#pragma unroll
    for (int t = 0; t < 4; ++t) {
      int row = wm + t * 16 + li;
      af[t] = *(const short8*)&sA[row * 40 + g * 8];
      int nl = wn + t * 16 + li;
      int phys = (nl << 2) | (g ^ ((nl >> 1) & 3));
      bfr[t] = *(const short8*)((const char*)sB + phys * 16);
    }
#pragma unroll
    for (int tm = 0; tm < 4; ++tm)
#pragma unroll
      for (int tn = 0; tn < 4; ++tn)
        acc[tm][tn] = __builtin_amdgcn_mfma_f32_16x16x32_bf16(af[tm], bfr[tn], acc[tm][tn], 0, 0, 0);
  }

  float dh[4], wa[4];
#pragma unroll
  for (int tn = 0; tn < 4; ++tn) {
    int n = nb * 128 + wn + tn * 16 + li;
    dh[tn] = dech[(size_t)bb * DIM + n];
    wa[tn] = w_attn[n];
  }
#pragma unroll
  for (int tm = 0; tm < 4; ++tm) {
    int mrow = rb * 128 + wm + tm * 16 + g * 4;
#pragma unroll
    for (int r = 0; r < 4; ++r) {
      float v = 0.0f;
#pragma unroll
      for (int tn = 0; tn < 4; ++tn)
        v = fmaf(wa[tn], fast_tanh(acc[tm][tn][r] + dh[tn]), v);
      v += __shfl_xor(v, 1);
      v += __shfl_xor(v, 2);
      v += __shfl_xor(v, 4);
      v += __shfl_xor(v, 8);
      if (li == 0) atomicAdd(&score[mrow + r], v);
    }
  }
}

// ---------------------------------------------------------------------------
// Kernel 4: masked softmax per batch row. SCALING == 1.0 (folded out).
// ---------------------------------------------------------------------------
__global__ void k_softmax(const float* __restrict__ score, const int* __restrict__ enc_len,
                          float* __restrict__ attn) {
  int b = blockIdx.x, tid = threadIdx.x;
  int len = enc_len[b];
  __shared__ float red[256];
  float v[8];
  float m = -1e30f;
#pragma unroll
  for (int i = 0; i < 8; ++i) {
    int s = tid + i * 256;
    v[i] = score[(size_t)b * SEQ + s];
    if (s < len) m = fmaxf(m, v[i]);
  }
  red[tid] = m; __syncthreads();
  for (int st = 128; st > 0; st >>= 1) {
    if (tid < st) red[tid] = fmaxf(red[tid], red[tid + st]);
    __syncthreads();
  }
  float mx = red[0]; __syncthreads();
  float sum = 0.0f;
#pragma unroll
  for (int i = 0; i < 8; ++i) {
    int s = tid + i * 256;
    float e = (s < len) ? __expf(v[i] - mx) : 0.0f;
    v[i] = e; sum += e;
  }
  red[tid] = sum; __syncthreads();
  for (int st = 128; st > 0; st >>= 1) {
    if (tid < st) red[tid] += red[tid + st];
    __syncthreads();
  }
  float inv = 1.0f / red[0];
#pragma unroll
  for (int i = 0; i < 8; ++i)
    attn[(size_t)b * SEQ + tid + i * 256] = v[i] * inv;
}

// ---------------------------------------------------------------------------
// Kernel 5: ctx[b][e] += sum_s attn[b][s] * enc[b][s][e]   (memory-bound)
// grid (32 s-chunks of 64, 32 b) = 1024 blocks, 4/CU
// ---------------------------------------------------------------------------
__global__ void k_context(const float* __restrict__ enc, const float* __restrict__ attn,
                          const int* __restrict__ enc_len, float* __restrict__ ctx) {
  int b = blockIdx.y, sc = blockIdx.x;
  int len = enc_len[b];
  int s0 = sc * 64;
  if (s0 >= len) return;
  int cnt = min(64, len - s0);
  int tid = threadIdx.x;
  const float* base = enc + ((size_t)b * SEQ + s0) * DIM + tid * 4;
  const float* ap   = attn + (size_t)b * SEQ + s0;
  float a0 = 0.f, a1 = 0.f, a2 = 0.f, a3 = 0.f;
  for (int i = 0; i < cnt; ++i) {
    float a = ap[i];
    float4 x = *(const float4*)(base + (size_t)i * DIM);
    a0 = fmaf(a, x.x, a0); a1 = fmaf(a, x.y, a1);
    a2 = fmaf(a, x.z, a2); a3 = fmaf(a, x.w, a3);
  }
  float* c = ctx + (size_t)b * DIM + tid * 4;
  atomicAdd(c + 0, a0); atomicAdd(c + 1, a1);
  atomicAdd(c + 2, a2); atomicAdd(c + 3, a3);
}

// ---------------------------------------------------------------------------
// Kernel 6: out[b][o] += ctx[b, z-chunk] @ W_out[z-chunk, o]  (split-K x8)
// chunk 0 adds b_out; out pre-zeroed via memset
// ---------------------------------------------------------------------------
__global__ void k_out(const float* __restrict__ ctx, const float* __restrict__ W_out,
                      const float* __restrict__ b_out, float* __restrict__ out) {
  int b = blockIdx.y, z = blockIdx.z;
  int o = blockIdx.x * 256 + threadIdx.x;
  float acc = (z == 0) ? b_out[o] : 0.0f;
  const float* cr = ctx + (size_t)b * DIM + z * 128;
  const float* wc = W_out + (size_t)z * 128 * DIM + o;
#pragma unroll 8
  for (int e = 0; e < 128; ++e)
    acc = fmaf(cr[e], wc[(size_t)e * DIM], acc);
  atomicAdd(&out[(size_t)b * DIM + o], acc);
}

// ---------------------------------------------------------------------------
extern "C" void kernel_launch(void* const* d_in, const int* in_sizes, int n_in,
                              void* d_out, int out_size, void* d_ws, size_t ws_size,
                              hipStream_t stream) {
  (void)in_sizes; (void)n_in; (void)out_size;
  const float* enc_states = (const float*)d_in[0];   // [32,2048,1024]
  const float* dec_states = (const float*)d_in[1];   // [32,1024]
  const float* W_enc      = (const float*)d_in[2];   // [1024,1024]
  const float* b_enc      = (const float*)d_in[3];   // [1024]
  const float* W_dec      = (const float*)d_in[4];   // [1024,1024]
  const float* b_dec      = (const float*)d_in[5];   // [1024]
  const float* w_attn     = (const float*)d_in[6];   // [1024]
  const float* W_out      = (const float*)d_in[7];   // [1024,1024]
  const float* b_out      = (const float*)d_in[8];   // [1024]
  const int*   enc_len    = (const int*)  d_in[9];   // [32]

  float* out_ctx  = (float*)d_out;                   // [32,1024]
  float* out_attn = (float*)d_out + BATCH * DIM;     // [32,2048]

  // workspace layout:
  //   Wt    @ 0        : 2 MB   (bf16 W_enc^T)
  //   score @ 2 MB     : 256 KB (zeroed)
  //   ctx   @ 2.25 MB  : 128 KB (zeroed)
  //   dech  @ 2.375 MB : 128 KB (zeroed)
  //   Abf   @ 3 MB     : 128 MB (bf16 enc_states) -- fast path only
  char* ws = (char*)d_ws;
  unsigned short* Wt  = (unsigned short*)ws;
  float* score = (float*)(ws + (2u << 20));
  float* ctx   = (float*)(ws + (2u << 20) + 262144);
  float* dech  = (float*)(ws + (2u << 20) + 262144 + 131072);
  unsigned short* Abf = (unsigned short*)(ws + (3u << 20));
  const bool fast = ws_size >= ((size_t)(3u << 20) + ((size_t)MROWS * DIM * 2));

  // zero score + ctx + dech (all atomically accumulated)
  hipMemsetAsync(ws + (2u << 20), 0, 262144 + 131072 + 131072, stream);
  // zero out_ctx (atomically accumulated by k_out)
  hipMemsetAsync(d_out, 0, (size_t)BATCH * DIM * sizeof(float), stream);

  k_transpose<<<dim3(32, 32), dim3(32, 8), 0, stream>>>(W_enc, Wt);
  k_dech<<<dim3(4, BATCH, 8), 256, 0, stream>>>(dec_states, W_dec, b_dec, b_enc, dech);
  if (fast) {
    k_convert<<<dim3(SEQ / 8, BATCH), 256, 0, stream>>>(enc_states, enc_len, Abf);
    k_gemm_bf16<<<4096, 256, 0, stream>>>(Abf, Wt, dech, w_attn, enc_len, score);
  } else {
    k_gemm_f32<<<4096, 256, 0, stream>>>(enc_states, Wt, dech, w_attn, enc_len, score);
  }
  k_softmax<<<BATCH, 256, 0, stream>>>(score, enc_len, out_attn);
  k_context<<<dim3(32, BATCH), 256, 0, stream>>>(enc_states, out_attn, enc_len, ctx);
  k_out<<<dim3(4, BATCH, 8), 256, 0, stream>>>(ctx, W_out, b_out, out_ctx);
}